// Round 6
// baseline (1439.619 us; speedup 1.0000x reference)
//
#include <hip/hip_runtime.h>
#include <math.h>

#define BB 2
#define NN 8192
#define NPTS (BB*NN)

typedef unsigned long long u64;

// ---------------- zero init (g2/g3 atomic-max targets) ----------------
__global__ __launch_bounds__(256) void zero_kernel(float* p, int n){
  int i = blockIdx.x*256 + threadIdx.x;
  if (i < n) p[i] = 0.f;
}

// ---------------- KNN helpers: branchless bitonic primitives ----------------
__device__ __forceinline__ void ce(u64& a, u64& b){
  u64 lo = a < b ? a : b;
  u64 hi = a < b ? b : a;
  a = lo; b = hi;
}

// cleans a bitonic 16-sequence into ascending order
__device__ __forceinline__ void bclean16(u64 e[16]){
  #pragma unroll
  for (int i=0;i<8;++i) ce(e[i], e[i+8]);
  #pragma unroll
  for (int g=0; g<2; ++g){
    #pragma unroll
    for (int i=0;i<4;++i) ce(e[g*8+i], e[g*8+i+4]);
  }
  #pragma unroll
  for (int g=0; g<4; ++g){
    #pragma unroll
    for (int i=0;i<2;++i) ce(e[g*4+i], e[g*4+i+2]);
  }
  #pragma unroll
  for (int g=0; g<8; ++g) ce(e[g*2], e[g*2+1]);
}

// merge own sorted-16 with partner's (lane^maskXor) sorted-16, keep smallest 16
__device__ __forceinline__ void merge_keep16(u64 e[16], int maskXor){
  u64 p[16];
  #pragma unroll
  for (int i=0;i<16;++i) p[i] = __shfl_xor(e[i], maskXor);
  #pragma unroll
  for (int i=0;i<16;++i){ u64 o = p[15-i]; e[i] = e[i] < o ? e[i] : o; }
  bclean16(e);
}

// ---------------- KNN: one wave per point ----------------
__global__ __launch_bounds__(64) void knn_kernel(const float* __restrict__ pts, int* __restrict__ knn){
  const int point = blockIdx.x;           // 0..16383
  const int b = point >> 13;
  const int n = point & (NN-1);
  const int lane = threadIdx.x;
  const float* pb = pts + (size_t)b*NN*3;
  const float px = pb[(size_t)n*3+0];
  const float py = pb[(size_t)n*3+1];
  const float pz = pb[(size_t)n*3+2];

  // fast path: per-lane branchless sorted-4 of 128 candidates
  u64 k0=~0ull, k1=~0ull, k2=~0ull, k3=~0ull;
  #pragma unroll 4
  for (int t=0; t<128; ++t){
    int m = lane + (t<<6);
    float dx = pb[(size_t)m*3+0] - px;
    float dy = pb[(size_t)m*3+1] - py;
    float dz = pb[(size_t)m*3+2] - pz;
    float dist = dx*dx + dy*dy + dz*dz;
    u64 c = ((u64)__float_as_uint(dist) << 32) | (unsigned)m;
    c = (m == n) ? ~0ull : c;             // exclude self
    bool l3 = c < k3, l2 = c < k2, l1 = c < k1, l0 = c < k0;
    k3 = l3 ? (l2 ? k2 : c) : k3;
    k2 = l2 ? (l1 ? k1 : c) : k2;
    k1 = l1 ? (l0 ? k0 : c) : k1;
    k0 = l0 ? c : k0;
  }
  const u64 k3s = k3;                     // lane's 4th-smallest (for exactness check)

  // wave-exact merge tree
  u64 e[16];
  {
    // xor 1: sorted-4 + sorted-4 -> sorted-8 (both lanes compute identical result)
    u64 p0=__shfl_xor(k0,1), p1=__shfl_xor(k1,1), p2=__shfl_xor(k2,1), p3=__shfl_xor(k3,1);
    e[0]=k0; e[1]=k1; e[2]=k2; e[3]=k3;
    e[4]=p3; e[5]=p2; e[6]=p1; e[7]=p0;   // partner descending -> bitonic 8
    ce(e[0],e[4]); ce(e[1],e[5]); ce(e[2],e[6]); ce(e[3],e[7]);
    ce(e[0],e[2]); ce(e[1],e[3]); ce(e[4],e[6]); ce(e[5],e[7]);
    ce(e[0],e[1]); ce(e[2],e[3]); ce(e[4],e[5]); ce(e[6],e[7]);
  }
  {
    // xor 2: sorted-8 + sorted-8 -> sorted-16 (exact, keeps all)
    u64 p[8];
    #pragma unroll
    for (int i=0;i<8;++i) p[i] = __shfl_xor(e[i], 2);
    #pragma unroll
    for (int i=0;i<8;++i) e[8+i] = p[7-i];
    bclean16(e);
  }
  merge_keep16(e, 4);
  merge_keep16(e, 8);
  merge_keep16(e, 16);
  merge_keep16(e, 32);
  // all lanes now hold identical global sorted-16

  const u64 T = e[15];                    // 16th smallest key
  u64 bal = __ballot(k3s < T);            // lane may have held a 5th value < T
  if (bal == 0){
    if (lane == 0){
      #pragma unroll
      for (int i=0;i<16;++i) knn[(size_t)point*16 + i] = (int)(unsigned)(e[i] & 0xffffffffu);
    }
    return;
  }

  // slow path (~0.5% of waves): known-correct 16-deep sorted insert + extraction
  float d[16]; int id[16];
  #pragma unroll
  for (int j=0;j<16;++j){ d[j]=INFINITY; id[j]=0x7fffffff; }
  for (int m = lane; m < NN; m += 64){
    if (m == n) continue;
    float dx = pb[(size_t)m*3+0] - px;
    float dy = pb[(size_t)m*3+1] - py;
    float dz = pb[(size_t)m*3+2] - pz;
    float dist = dx*dx + dy*dy + dz*dz;
    if (dist < d[15] || (dist == d[15] && m < id[15])){
      float cd = dist; int ci = m;
      #pragma unroll
      for (int j=0;j<16;++j){
        bool sw = (cd < d[j]) || (cd == d[j] && ci < id[j]);
        float td = sw ? d[j] : cd; int ti = sw ? id[j] : ci;
        d[j]  = sw ? cd : d[j];
        id[j] = sw ? ci : id[j];
        cd = td; ci = ti;
      }
    }
  }
  for (int r=0; r<16; ++r){
    float bd = d[0]; int bi = id[0];
    for (int off=32; off>=1; off>>=1){
      float od = __shfl_xor(bd, off);
      int   oi = __shfl_xor(bi, off);
      bool take = (od < bd) || (od == bd && oi < bi);
      bd = take ? od : bd; bi = take ? oi : bi;
    }
    if (d[0] == bd && id[0] == bi){
      knn[(size_t)point*16 + r] = bi;
      #pragma unroll
      for (int j=0;j<15;++j){ d[j]=d[j+1]; id[j]=id[j+1]; }
      d[15]=INFINITY; id[15]=0x7fffffff;
    }
  }
}

// ------------- neighbor MLP + pool + ftr_1 (thread = point*16+k) -------------
__global__ __launch_bounds__(256) void nbr_kernel(
    const float* __restrict__ pts, const int* __restrict__ knn,
    const float* __restrict__ w1, const float* __restrict__ b1,
    const float* __restrict__ w2, const float* __restrict__ b2,
    const float* __restrict__ wp, const float* __restrict__ bp,
    const float* __restrict__ w3, const float* __restrict__ b3,
    float* __restrict__ ftr1)
{
  __shared__ float sw1[7*16], sb1[16], sw2[16*32], sb2[32], swp[3*32], sbp[32], sw3[64*32], sb3[32];
  for (int t = threadIdx.x; t < 7*16;  t += 256) sw1[t] = w1[t];
  for (int t = threadIdx.x; t < 16;    t += 256) sb1[t] = b1[t];
  for (int t = threadIdx.x; t < 16*32; t += 256) sw2[t] = w2[t];
  for (int t = threadIdx.x; t < 32;    t += 256) sb2[t] = b2[t];
  for (int t = threadIdx.x; t < 3*32;  t += 256) swp[t] = wp[t];
  for (int t = threadIdx.x; t < 32;    t += 256) sbp[t] = bp[t];
  for (int t = threadIdx.x; t < 64*32; t += 256) sw3[t] = w3[t];
  for (int t = threadIdx.x; t < 32;    t += 256) sb3[t] = b3[t];
  __syncthreads();
  int gt = blockIdx.x*256 + threadIdx.x;
  int point = gt >> 4;
  int k = gt & 15;
  int b = point >> 13;
  float ax = pts[(size_t)point*3+0];
  float ay = pts[(size_t)point*3+1];
  float az = pts[(size_t)point*3+2];
  int idx = knn[(size_t)point*16 + k] & (NN-1);   // clamp: insurance against bad indices
  size_t nb = ((size_t)b*NN + idx)*3;
  float rx = pts[nb+0] - ax;
  float ry = pts[nb+1] - ay;
  float rz = pts[nb+2] - az;
  float dd = sqrtf(rx*rx + ry*ry + rz*rz + 1e-8f);
  float in7[7] = {ax, ay, az, rx, ry, rz, dd};
  float h16[16];
  #pragma unroll
  for (int j=0;j<16;++j){
    float a = sb1[j];
    #pragma unroll
    for (int c=0;c<7;++c) a += in7[c]*sw1[c*16+j];
    h16[j] = fmaxf(a, 0.f);
  }
  float h32[32];
  #pragma unroll
  for (int j=0;j<32;++j){
    float a = sb2[j];
    #pragma unroll
    for (int c=0;c<16;++c) a += h16[c]*sw2[c*32+j];
    h32[j] = fmaxf(a, 0.f);
  }
  #pragma unroll
  for (int j=0;j<32;++j){
    h32[j] = fmaxf(h32[j], __shfl_xor(h32[j], 8));
    h32[j] = fmaxf(h32[j], __shfl_xor(h32[j], 4));
    h32[j] = fmaxf(h32[j], __shfl_xor(h32[j], 2));
    h32[j] = fmaxf(h32[j], __shfl_xor(h32[j], 1));
  }
  if (k == 0){
    float lift[32];
    #pragma unroll
    for (int j=0;j<32;++j){
      float a = sbp[j] + ax*swp[0*32+j] + ay*swp[1*32+j] + az*swp[2*32+j];
      lift[j] = fmaxf(a, 0.f);
    }
    #pragma unroll
    for (int j=0;j<32;++j){
      float a = sb3[j];
      #pragma unroll
      for (int c=0;c<32;++c) a += lift[c]*sw3[c*32+j];
      #pragma unroll
      for (int c=0;c<32;++c) a += h32[c]*sw3[(32+c)*32+j];
      ftr1[(size_t)point*32 + j] = fmaxf(a, 0.f);
    }
  }
}

// ------- fused residual SMLP: Y = relu( relu(X@wa+ba)@wb + bb + X@ws + bs ) -------
// X = [s0 (w0 cols) | s1 (KIN-w0 cols, batch-broadcast if bc1)], per 16-row tile.
template<int KIN, int JM>
__global__ __launch_bounds__(256) void resblock_kernel(
    const float* __restrict__ s0, int w0,
    const float* __restrict__ s1, int bc1,
    const float* __restrict__ wa, const float* __restrict__ ba,
    const float* __restrict__ wb, const float* __restrict__ bb,
    const float* __restrict__ wsk, const float* __restrict__ bs,
    float* __restrict__ Y)
{
  __shared__ float xs[KIN*16];
  __shared__ float as_[JM*16];
  const int n0 = blockIdx.x * 16;
  for (int t = threadIdx.x; t < 16*KIN; t += 256){
    int p = t / KIN, c = t - p*KIN;
    int row = n0 + p;
    float v = (c < w0) ? s0[(size_t)row*w0 + c]
                       : s1[(size_t)(bc1 ? (row>>13) : row)*(KIN-w0) + (c-w0)];
    xs[c*16 + p] = v;
  }
  __syncthreads();
  constexpr int ROWS = (JM == 64) ? 4 : 8;   // Jt = 256/(16/ROWS) == JM
  const int j  = threadIdx.x % JM;
  const int p0 = (threadIdx.x / JM) * ROWS;
  const float4* xs4 = (const float4*)xs;
  // phase A: A^T in LDS
  {
    float acc[ROWS];
    #pragma unroll
    for (int r=0;r<ROWS;++r) acc[r]=0.f;
    for (int k=0;k<KIN;++k){
      float w = wa[(size_t)k*JM + j];
      #pragma unroll
      for (int q=0;q<ROWS/4;++q){
        float4 xv = xs4[k*4 + (p0>>2) + q];
        acc[q*4+0] += xv.x*w; acc[q*4+1] += xv.y*w;
        acc[q*4+2] += xv.z*w; acc[q*4+3] += xv.w*w;
      }
    }
    float bv = ba[j];
    #pragma unroll
    for (int r=0;r<ROWS;++r) as_[j*16 + p0 + r] = fmaxf(acc[r] + bv, 0.f);
  }
  __syncthreads();
  // phase B: Y = relu(A@wb + bb + X@ws + bs)
  {
    const float4* as4 = (const float4*)as_;
    float acc[ROWS];
    #pragma unroll
    for (int r=0;r<ROWS;++r) acc[r]=0.f;
    for (int k=0;k<JM;++k){
      float w = wb[(size_t)k*JM + j];
      #pragma unroll
      for (int q=0;q<ROWS/4;++q){
        float4 xv = as4[k*4 + (p0>>2) + q];
        acc[q*4+0] += xv.x*w; acc[q*4+1] += xv.y*w;
        acc[q*4+2] += xv.z*w; acc[q*4+3] += xv.w*w;
      }
    }
    for (int k=0;k<KIN;++k){
      float w = wsk[(size_t)k*JM + j];
      #pragma unroll
      for (int q=0;q<ROWS/4;++q){
        float4 xv = xs4[k*4 + (p0>>2) + q];
        acc[q*4+0] += xv.x*w; acc[q*4+1] += xv.y*w;
        acc[q*4+2] += xv.z*w; acc[q*4+3] += xv.w*w;
      }
    }
    float bv = bb[j] + bs[j];
    #pragma unroll
    for (int r=0;r<ROWS;++r)
      Y[(size_t)(n0 + p0 + r)*JM + j] = fmaxf(acc[r] + bv, 0.f);
  }
}

// ------------- column max over N per batch (relu inputs >= 0) -------------
__global__ __launch_bounds__(256) void colmax_kernel(const float* __restrict__ X, float* __restrict__ out, int J){
  int b  = blockIdx.y;
  int n0 = blockIdx.x * 256;
  int f  = threadIdx.x % J;
  int r0 = threadIdx.x / J;
  int step = 256 / J;
  float vm = 0.f;
  for (int n = n0 + r0; n < n0 + 256; n += step)
    vm = fmaxf(vm, X[((size_t)b*NN + n)*J + f]);
  atomicMax((int*)&out[b*J + f], __float_as_int(vm));
}

// ---- fused: ftr4-tile = relu(concat@fuse) in LDS; att logits + online softmax ----
// One block (512 thr, 8 waves) handles 64 rows (4 sub-tiles of 16).
// Emits per-column (m, s, a, fmax) partials. f4 tile stored row-major [16][512].
__global__ __launch_bounds__(512) void fuseatt_kernel(
    const float* __restrict__ f1, const float* __restrict__ f2,
    const float* __restrict__ f3, const float* __restrict__ g3,
    const float* __restrict__ fw, const float* __restrict__ fb,
    const float* __restrict__ aw, const float* __restrict__ ab,
    float4* __restrict__ part)
{
  __shared__ float xs[352*16];    // [c][p], 22528 B
  __shared__ float f4[16*512];    // [r][jj], 32768 B
  const int chunk = blockIdx.x;   // 0..255
  const int tid = threadIdx.x;    // 0..511 == output column jj
  float m=-INFINITY, s=0.f, a=0.f, fx=0.f;
  const float4* xs4 = (const float4*)xs;
  const float4* f4r = (const float4*)f4;      // f4[r][4*k4 .. +3] = f4r[r*128 + k4]
  for (int sub=0; sub<4; ++sub){
    __syncthreads();
    const int n0 = chunk*64 + sub*16;
    // stage xs, p-fast (consecutive tids -> consecutive LDS addresses)
    for (int t = tid; t < 16*352; t += 512){
      int c = t >> 4, p = t & 15;
      int row = n0 + p;
      float v;
      if (c < 32)       v = f1[(size_t)row*32 + c];
      else if (c < 96)  v = f2[(size_t)row*64 + (c-32)];
      else if (c < 224) v = f3[(size_t)row*128 + (c-96)];
      else              v = g3[(size_t)(row>>13)*128 + (c-224)];
      xs[c*16 + p] = v;
    }
    __syncthreads();
    // fuse GEMM: thread -> column tid; K=352 grouped by 4 (4 loads in flight)
    {
      float acc[16];
      #pragma unroll
      for (int r=0;r<16;++r) acc[r]=0.f;
      for (int k=0;k<352;k+=4){
        float w0 = fw[(size_t)(k+0)*512 + tid];
        float w1 = fw[(size_t)(k+1)*512 + tid];
        float w2 = fw[(size_t)(k+2)*512 + tid];
        float w3 = fw[(size_t)(k+3)*512 + tid];
        #pragma unroll
        for (int q=0;q<4;++q){
          float4 x0 = xs4[(k+0)*4 + q];
          float4 x1 = xs4[(k+1)*4 + q];
          float4 x2 = xs4[(k+2)*4 + q];
          float4 x3 = xs4[(k+3)*4 + q];
          acc[q*4+0] += x0.x*w0 + x1.x*w1 + x2.x*w2 + x3.x*w3;
          acc[q*4+1] += x0.y*w0 + x1.y*w1 + x2.y*w2 + x3.y*w3;
          acc[q*4+2] += x0.z*w0 + x1.z*w1 + x2.z*w2 + x3.z*w3;
          acc[q*4+3] += x0.w*w0 + x1.w*w1 + x2.w*w2 + x3.w*w3;
        }
      }
      float bv = fb[tid];
      #pragma unroll
      for (int r=0;r<16;++r) f4[r*512 + tid] = fmaxf(acc[r] + bv, 0.f);
    }
    __syncthreads();
    // att GEMM over the LDS ftr4 tile + online softmax update
    {
      float acc[16];
      #pragma unroll
      for (int r=0;r<16;++r) acc[r]=0.f;
      #pragma unroll 2
      for (int k4=0;k4<128;++k4){
        int k = k4*4;
        float w0 = aw[(size_t)(k+0)*512 + tid];
        float w1 = aw[(size_t)(k+1)*512 + tid];
        float w2 = aw[(size_t)(k+2)*512 + tid];
        float w3 = aw[(size_t)(k+3)*512 + tid];
        #pragma unroll
        for (int r=0;r<16;++r){
          float4 fv = f4r[r*128 + k4];
          acc[r] += fv.x*w0 + fv.y*w1 + fv.z*w2 + fv.w*w3;
        }
      }
      float lb = ab[tid];
      #pragma unroll
      for (int r=0;r<16;++r){
        float l = acc[r] + lb;
        float x = f4[r*512 + tid];
        float mn = fmaxf(m, l);
        float e0 = __expf(m - mn);
        float e1 = __expf(l - mn);
        s = s*e0 + e1;
        a = a*e0 + x*e1;
        m = mn;
        fx = fmaxf(fx, x);
      }
    }
  }
  part[(size_t)chunk*512 + tid] = make_float4(m, s, a, fx);
}

__global__ __launch_bounds__(256) void attmerge_kernel(const float4* __restrict__ part, float* __restrict__ feat){
  int t = blockIdx.x*256 + threadIdx.x;  // 0..1023
  if (t >= BB*512) return;
  int b = t >> 9, f = t & 511;
  float m=-INFINITY, s=0.f, a=0.f, fx=0.f;
  for (int c=0;c<128;++c){               // 128 chunks per batch
    float4 p = part[((size_t)(b*128 + c))*512 + f];
    float mn = fmaxf(m, p.x);
    float e0 = __expf(m - mn), e1 = __expf(p.x - mn);
    s = s*e0 + p.y*e1;
    a = a*e0 + p.z*e1;
    m = mn;
    fx = fmaxf(fx, p.w);
  }
  feat[(size_t)b*1024 + f] = fx;
  feat[(size_t)b*1024 + 512 + f] = a / s;
}

// ------------- head MLP (N=2 rows) -------------
__global__ __launch_bounds__(256) void head_kernel(
    const float* __restrict__ X, const float* __restrict__ W, const float* __restrict__ bias,
    float* __restrict__ Y, int K, int J, int relu_flag)
{
  int j = blockIdx.x*256 + threadIdx.x;
  if (j >= J) return;
  float bv = bias[j];
  float a0 = bv, a1 = bv;
  for (int k=0;k<K;++k){
    float w = W[(size_t)k*J + j];
    a0 += X[k]   * w;
    a1 += X[K+k] * w;
  }
  if (relu_flag){ a0 = fmaxf(a0,0.f); a1 = fmaxf(a1,0.f); }
  Y[j] = a0; Y[J+j] = a1;
}

extern "C" void kernel_launch(void* const* d_in, const int* in_sizes, int n_in,
                              void* d_out, int out_size, void* d_ws, size_t ws_size,
                              hipStream_t stream)
{
  const float* pts    = (const float*)d_in[0];
  const float* na1w1  = (const float*)d_in[1];
  const float* na1b1  = (const float*)d_in[2];
  const float* na1w2  = (const float*)d_in[3];
  const float* na1b2  = (const float*)d_in[4];
  const float* na2w   = (const float*)d_in[5];
  const float* na2b   = (const float*)d_in[6];
  const float* na3w   = (const float*)d_in[7];
  const float* na3b   = (const float*)d_in[8];
  const float* r1aw   = (const float*)d_in[9];
  const float* r1ab   = (const float*)d_in[10];
  const float* r1bw   = (const float*)d_in[11];
  const float* r1bb   = (const float*)d_in[12];
  const float* r1sw   = (const float*)d_in[13];
  const float* r1sb   = (const float*)d_in[14];
  const float* r2aw   = (const float*)d_in[15];
  const float* r2ab   = (const float*)d_in[16];
  const float* r2bw   = (const float*)d_in[17];
  const float* r2bb   = (const float*)d_in[18];
  const float* r2sw   = (const float*)d_in[19];
  const float* r2sb   = (const float*)d_in[20];
  const float* fusew  = (const float*)d_in[21];
  const float* fuseb  = (const float*)d_in[22];
  const float* attw   = (const float*)d_in[23];
  const float* attb   = (const float*)d_in[24];
  const float* fc1w   = (const float*)d_in[25];
  const float* fc1b   = (const float*)d_in[26];
  const float* fc2w   = (const float*)d_in[27];
  const float* fc2b   = (const float*)d_in[28];
  const float* fc3w   = (const float*)d_in[29];
  const float* fc3b   = (const float*)d_in[30];

  // Layout-assumption guards: wrong => zeros output (visible absmax fail, not a fault)
  if (n_in < 31) return;
  if (in_sizes[0] != NPTS*3) return;        // pts
  if (in_sizes[21] != 352*512) return;      // fuse_w
  if (in_sizes[29] != 1024*1024) return;    // fc3_w

  // Workspace layout (float offsets). Peak 4,199,808 floats = 16.8 MB.
  const size_t o_ftr1 = 0;              // 524288
  const size_t o_ftr2 = 524288;         // 1048576
  const size_t o_ftr3 = 1572864;        // 2097152
  const size_t o_knn  = 1572864;        // 262144 ints, dead before ftr3 written
  const size_t o_part = 3670016;        // 524288 (256 chunks * 512 * float4)
  const size_t o_g2   = 4194304;        // 128
  const size_t o_g3   = 4194432;        // 256
  const size_t o_feat = 4194688;        // 2048
  const size_t o_h1   = 4196736;        // 1024
  const size_t o_h2   = 4197760;        // 2048  -> end 4199808
  const size_t needed_bytes = 4199808ull * 4ull;
  if (ws_size < needed_bytes) return;   // diagnostic: zeros output instead of faulting

  float* ws = (float*)d_ws;
  float*  ftr1 = ws + o_ftr1;
  float*  ftr2 = ws + o_ftr2;
  float*  ftr3 = ws + o_ftr3;
  int*    knn  = (int*)(ws + o_knn);
  float4* part = (float4*)(ws + o_part);
  float*  g2   = ws + o_g2;
  float*  g3   = ws + o_g3;
  float*  feat = ws + o_feat;
  float*  h1   = ws + o_h1;
  float*  h2   = ws + o_h2;

  // 0. zero atomic-max targets (g2 128 + g3 256, contiguous)
  zero_kernel<<<2, 256, 0, stream>>>(g2, 384);
  // 1. KNN
  knn_kernel<<<NPTS, 64, 0, stream>>>(pts, knn);
  // 2. neighbor MLP + pool + ftr_1
  nbr_kernel<<<NPTS*16/256, 256, 0, stream>>>(pts, knn, na1w1, na1b1, na1w2, na1b2,
                                              na2w, na2b, na3w, na3b, ftr1);
  // 3. res block 1: ftr1(32) -> ftr2(64), fused
  resblock_kernel<32,64><<<NPTS/16, 256, 0, stream>>>(ftr1, 32, nullptr, 0,
                                                      r1aw, r1ab, r1bw, r1bb, r1sw, r1sb, ftr2);
  // 4. g2
  colmax_kernel<<<dim3(32,2), 256, 0, stream>>>(ftr2, g2, 64);
  // 5. res block 2: [ftr2|g2](128) -> ftr3(128), fused, g2 batch-broadcast
  resblock_kernel<128,128><<<NPTS/16, 256, 0, stream>>>(ftr2, 64, g2, 1,
                                                        r2aw, r2ab, r2bw, r2bb, r2sw, r2sb, ftr3);
  // 6. g3
  colmax_kernel<<<dim3(32,2), 256, 0, stream>>>(ftr3, g3, 128);
  // 7+8. fused fuse-GEMM + att-GEMM + online softmax partials, then merge
  fuseatt_kernel<<<NPTS/64, 512, 0, stream>>>(ftr1, ftr2, ftr3, g3,
                                              fusew, fuseb, attw, attb, part);
  attmerge_kernel<<<4, 256, 0, stream>>>(part, feat);
  // 9. head MLP (N=2 rows)
  head_kernel<<<2, 256, 0, stream>>>(feat, fc1w, fc1b, h1, 1024, 512, 1);
  head_kernel<<<4, 256, 0, stream>>>(h1,   fc2w, fc2b, h2, 512, 1024, 1);
  head_kernel<<<4, 256, 0, stream>>>(h2,   fc3w, fc3b, (float*)d_out, 1024, 1024, 0);
}

// Round 7
// 1084.266 us; speedup vs baseline: 1.3277x; 1.3277x over previous
//
#include <hip/hip_runtime.h>
#include <math.h>

#define BB 2
#define NN 8192
#define NPTS (BB*NN)

typedef unsigned long long u64;
typedef short s16;
typedef __attribute__((ext_vector_type(8))) short short8v;
typedef __attribute__((ext_vector_type(4))) float f32x4;

__device__ __forceinline__ unsigned short f2bf(float v){
  unsigned u = __float_as_uint(v);
  return (unsigned short)((u + 0x7FFFu + ((u >> 16) & 1u)) >> 16);
}
__device__ __forceinline__ float bf2f(unsigned short h){
  return __uint_as_float(((unsigned)h) << 16);
}

// ---------------- zero init (g2/g3 atomic-max targets) ----------------
__global__ __launch_bounds__(256) void zero_kernel(float* p, int n){
  int i = blockIdx.x*256 + threadIdx.x;
  if (i < n) p[i] = 0.f;
}

// ---------------- KNN helpers: branchless bitonic primitives ----------------
__device__ __forceinline__ void ce(u64& a, u64& b){
  u64 lo = a < b ? a : b;
  u64 hi = a < b ? b : a;
  a = lo; b = hi;
}

__device__ __forceinline__ void bclean16(u64 e[16]){
  #pragma unroll
  for (int i=0;i<8;++i) ce(e[i], e[i+8]);
  #pragma unroll
  for (int g=0; g<2; ++g){
    #pragma unroll
    for (int i=0;i<4;++i) ce(e[g*8+i], e[g*8+i+4]);
  }
  #pragma unroll
  for (int g=0; g<4; ++g){
    #pragma unroll
    for (int i=0;i<2;++i) ce(e[g*4+i], e[g*4+i+2]);
  }
  #pragma unroll
  for (int g=0; g<8; ++g) ce(e[g*2], e[g*2+1]);
}

__device__ __forceinline__ void merge_keep16(u64 e[16], int maskXor){
  u64 p[16];
  #pragma unroll
  for (int i=0;i<16;++i) p[i] = __shfl_xor(e[i], maskXor);
  #pragma unroll
  for (int i=0;i<16;++i){ u64 o = p[15-i]; e[i] = e[i] < o ? e[i] : o; }
  bclean16(e);
}

// ---------------- KNN: one wave per point ----------------
__global__ __launch_bounds__(64) void knn_kernel(const float* __restrict__ pts, int* __restrict__ knn){
  const int point = blockIdx.x;
  const int b = point >> 13;
  const int n = point & (NN-1);
  const int lane = threadIdx.x;
  const float* pb = pts + (size_t)b*NN*3;
  const float px = pb[(size_t)n*3+0];
  const float py = pb[(size_t)n*3+1];
  const float pz = pb[(size_t)n*3+2];

  u64 k0=~0ull, k1=~0ull, k2=~0ull, k3=~0ull;
  #pragma unroll 4
  for (int t=0; t<128; ++t){
    int m = lane + (t<<6);
    float dx = pb[(size_t)m*3+0] - px;
    float dy = pb[(size_t)m*3+1] - py;
    float dz = pb[(size_t)m*3+2] - pz;
    float dist = dx*dx + dy*dy + dz*dz;
    u64 c = ((u64)__float_as_uint(dist) << 32) | (unsigned)m;
    c = (m == n) ? ~0ull : c;
    bool l3 = c < k3, l2 = c < k2, l1 = c < k1, l0 = c < k0;
    k3 = l3 ? (l2 ? k2 : c) : k3;
    k2 = l2 ? (l1 ? k1 : c) : k2;
    k1 = l1 ? (l0 ? k0 : c) : k1;
    k0 = l0 ? c : k0;
  }
  const u64 k3s = k3;

  u64 e[16];
  {
    u64 p0=__shfl_xor(k0,1), p1=__shfl_xor(k1,1), p2=__shfl_xor(k2,1), p3=__shfl_xor(k3,1);
    e[0]=k0; e[1]=k1; e[2]=k2; e[3]=k3;
    e[4]=p3; e[5]=p2; e[6]=p1; e[7]=p0;
    ce(e[0],e[4]); ce(e[1],e[5]); ce(e[2],e[6]); ce(e[3],e[7]);
    ce(e[0],e[2]); ce(e[1],e[3]); ce(e[4],e[6]); ce(e[5],e[7]);
    ce(e[0],e[1]); ce(e[2],e[3]); ce(e[4],e[5]); ce(e[6],e[7]);
  }
  {
    u64 p[8];
    #pragma unroll
    for (int i=0;i<8;++i) p[i] = __shfl_xor(e[i], 2);
    #pragma unroll
    for (int i=0;i<8;++i) e[8+i] = p[7-i];
    bclean16(e);
  }
  merge_keep16(e, 4);
  merge_keep16(e, 8);
  merge_keep16(e, 16);
  merge_keep16(e, 32);

  const u64 T = e[15];
  u64 bal = __ballot(k3s < T);
  if (bal == 0){
    if (lane == 0){
      #pragma unroll
      for (int i=0;i<16;++i) knn[(size_t)point*16 + i] = (int)(unsigned)(e[i] & 0xffffffffu);
    }
    return;
  }

  float d[16]; int id[16];
  #pragma unroll
  for (int j=0;j<16;++j){ d[j]=INFINITY; id[j]=0x7fffffff; }
  for (int m = lane; m < NN; m += 64){
    if (m == n) continue;
    float dx = pb[(size_t)m*3+0] - px;
    float dy = pb[(size_t)m*3+1] - py;
    float dz = pb[(size_t)m*3+2] - pz;
    float dist = dx*dx + dy*dy + dz*dz;
    if (dist < d[15] || (dist == d[15] && m < id[15])){
      float cd = dist; int ci = m;
      #pragma unroll
      for (int j=0;j<16;++j){
        bool sw = (cd < d[j]) || (cd == d[j] && ci < id[j]);
        float td = sw ? d[j] : cd; int ti = sw ? id[j] : ci;
        d[j]  = sw ? cd : d[j];
        id[j] = sw ? ci : id[j];
        cd = td; ci = ti;
      }
    }
  }
  for (int r=0; r<16; ++r){
    float bd = d[0]; int bi = id[0];
    for (int off=32; off>=1; off>>=1){
      float od = __shfl_xor(bd, off);
      int   oi = __shfl_xor(bi, off);
      bool take = (od < bd) || (od == bd && oi < bi);
      bd = take ? od : bd; bi = take ? oi : bi;
    }
    if (d[0] == bd && id[0] == bi){
      knn[(size_t)point*16 + r] = bi;
      #pragma unroll
      for (int j=0;j<15;++j){ d[j]=d[j+1]; id[j]=id[j+1]; }
      d[15]=INFINITY; id[15]=0x7fffffff;
    }
  }
}

// ------------- neighbor MLP + pool + ftr_1 (thread = point*16+k) -------------
__global__ __launch_bounds__(256) void nbr_kernel(
    const float* __restrict__ pts, const int* __restrict__ knn,
    const float* __restrict__ w1, const float* __restrict__ b1,
    const float* __restrict__ w2, const float* __restrict__ b2,
    const float* __restrict__ wp, const float* __restrict__ bp,
    const float* __restrict__ w3, const float* __restrict__ b3,
    float* __restrict__ ftr1)
{
  __shared__ float sw1[7*16], sb1[16], sw2[16*32], sb2[32], swp[3*32], sbp[32], sw3[64*32], sb3[32];
  for (int t = threadIdx.x; t < 7*16;  t += 256) sw1[t] = w1[t];
  for (int t = threadIdx.x; t < 16;    t += 256) sb1[t] = b1[t];
  for (int t = threadIdx.x; t < 16*32; t += 256) sw2[t] = w2[t];
  for (int t = threadIdx.x; t < 32;    t += 256) sb2[t] = b2[t];
  for (int t = threadIdx.x; t < 3*32;  t += 256) swp[t] = wp[t];
  for (int t = threadIdx.x; t < 32;    t += 256) sbp[t] = bp[t];
  for (int t = threadIdx.x; t < 64*32; t += 256) sw3[t] = w3[t];
  for (int t = threadIdx.x; t < 32;    t += 256) sb3[t] = b3[t];
  __syncthreads();
  int gt = blockIdx.x*256 + threadIdx.x;
  int point = gt >> 4;
  int k = gt & 15;
  int b = point >> 13;
  float ax = pts[(size_t)point*3+0];
  float ay = pts[(size_t)point*3+1];
  float az = pts[(size_t)point*3+2];
  int idx = knn[(size_t)point*16 + k] & (NN-1);
  size_t nb = ((size_t)b*NN + idx)*3;
  float rx = pts[nb+0] - ax;
  float ry = pts[nb+1] - ay;
  float rz = pts[nb+2] - az;
  float dd = sqrtf(rx*rx + ry*ry + rz*rz + 1e-8f);
  float in7[7] = {ax, ay, az, rx, ry, rz, dd};
  float h16[16];
  #pragma unroll
  for (int j=0;j<16;++j){
    float a = sb1[j];
    #pragma unroll
    for (int c=0;c<7;++c) a += in7[c]*sw1[c*16+j];
    h16[j] = fmaxf(a, 0.f);
  }
  float h32[32];
  #pragma unroll
  for (int j=0;j<32;++j){
    float a = sb2[j];
    #pragma unroll
    for (int c=0;c<16;++c) a += h16[c]*sw2[c*32+j];
    h32[j] = fmaxf(a, 0.f);
  }
  #pragma unroll
  for (int j=0;j<32;++j){
    h32[j] = fmaxf(h32[j], __shfl_xor(h32[j], 8));
    h32[j] = fmaxf(h32[j], __shfl_xor(h32[j], 4));
    h32[j] = fmaxf(h32[j], __shfl_xor(h32[j], 2));
    h32[j] = fmaxf(h32[j], __shfl_xor(h32[j], 1));
  }
  if (k == 0){
    float lift[32];
    #pragma unroll
    for (int j=0;j<32;++j){
      float a = sbp[j] + ax*swp[0*32+j] + ay*swp[1*32+j] + az*swp[2*32+j];
      lift[j] = fmaxf(a, 0.f);
    }
    #pragma unroll
    for (int j=0;j<32;++j){
      float a = sb3[j];
      #pragma unroll
      for (int c=0;c<32;++c) a += lift[c]*sw3[c*32+j];
      #pragma unroll
      for (int c=0;c<32;++c) a += h32[c]*sw3[(32+c)*32+j];
      ftr1[(size_t)point*32 + j] = fmaxf(a, 0.f);
    }
  }
}

// ------- fused residual SMLP (unchanged) -------
template<int KIN, int JM>
__global__ __launch_bounds__(256) void resblock_kernel(
    const float* __restrict__ s0, int w0,
    const float* __restrict__ s1, int bc1,
    const float* __restrict__ wa, const float* __restrict__ ba,
    const float* __restrict__ wb, const float* __restrict__ bb,
    const float* __restrict__ wsk, const float* __restrict__ bs,
    float* __restrict__ Y)
{
  __shared__ float xs[KIN*16];
  __shared__ float as_[JM*16];
  const int n0 = blockIdx.x * 16;
  for (int t = threadIdx.x; t < 16*KIN; t += 256){
    int p = t / KIN, c = t - p*KIN;
    int row = n0 + p;
    float v = (c < w0) ? s0[(size_t)row*w0 + c]
                       : s1[(size_t)(bc1 ? (row>>13) : row)*(KIN-w0) + (c-w0)];
    xs[c*16 + p] = v;
  }
  __syncthreads();
  constexpr int ROWS = (JM == 64) ? 4 : 8;
  const int j  = threadIdx.x % JM;
  const int p0 = (threadIdx.x / JM) * ROWS;
  const float4* xs4 = (const float4*)xs;
  {
    float acc[ROWS];
    #pragma unroll
    for (int r=0;r<ROWS;++r) acc[r]=0.f;
    for (int k=0;k<KIN;++k){
      float w = wa[(size_t)k*JM + j];
      #pragma unroll
      for (int q=0;q<ROWS/4;++q){
        float4 xv = xs4[k*4 + (p0>>2) + q];
        acc[q*4+0] += xv.x*w; acc[q*4+1] += xv.y*w;
        acc[q*4+2] += xv.z*w; acc[q*4+3] += xv.w*w;
      }
    }
    float bv = ba[j];
    #pragma unroll
    for (int r=0;r<ROWS;++r) as_[j*16 + p0 + r] = fmaxf(acc[r] + bv, 0.f);
  }
  __syncthreads();
  {
    const float4* as4 = (const float4*)as_;
    float acc[ROWS];
    #pragma unroll
    for (int r=0;r<ROWS;++r) acc[r]=0.f;
    for (int k=0;k<JM;++k){
      float w = wb[(size_t)k*JM + j];
      #pragma unroll
      for (int q=0;q<ROWS/4;++q){
        float4 xv = as4[k*4 + (p0>>2) + q];
        acc[q*4+0] += xv.x*w; acc[q*4+1] += xv.y*w;
        acc[q*4+2] += xv.z*w; acc[q*4+3] += xv.w*w;
      }
    }
    for (int k=0;k<KIN;++k){
      float w = wsk[(size_t)k*JM + j];
      #pragma unroll
      for (int q=0;q<ROWS/4;++q){
        float4 xv = xs4[k*4 + (p0>>2) + q];
        acc[q*4+0] += xv.x*w; acc[q*4+1] += xv.y*w;
        acc[q*4+2] += xv.z*w; acc[q*4+3] += xv.w*w;
      }
    }
    float bv = bb[j] + bs[j];
    #pragma unroll
    for (int r=0;r<ROWS;++r)
      Y[(size_t)(n0 + p0 + r)*JM + j] = fmaxf(acc[r] + bv, 0.f);
  }
}

// ------------- column max over N per batch -------------
__global__ __launch_bounds__(256) void colmax_kernel(const float* __restrict__ X, float* __restrict__ out, int J){
  int b  = blockIdx.y;
  int n0 = blockIdx.x * 256;
  int f  = threadIdx.x % J;
  int r0 = threadIdx.x / J;
  int step = 256 / J;
  float vm = 0.f;
  for (int n = n0 + r0; n < n0 + 256; n += step)
    vm = fmaxf(vm, X[((size_t)b*NN + n)*J + f]);
  atomicMax((int*)&out[b*J + f], __float_as_int(vm));
}

// ------- weight pack: W[K,512] f32 -> bf16 MFMA B-fragment order -------
// block = (kt*32 + nt); lane holds B[kt*32+(l>>4)*8+i][nt*16+(l&15)], i=0..7 contiguous.
__global__ __launch_bounds__(64) void packw_kernel(const float* __restrict__ W, s16* __restrict__ out){
  int kt = blockIdx.x >> 5, nt = blockIdx.x & 31;
  int lane = threadIdx.x;
  int k0 = kt*32 + ((lane>>4)<<3);
  int n  = nt*16 + (lane & 15);
  s16 v[8];
  #pragma unroll
  for (int i=0;i<8;++i) v[i] = (s16)f2bf(W[(size_t)(k0+i)*512 + n]);
  *(short8v*)(out + (((size_t)blockIdx.x)*64 + lane)*8) = *(short8v*)v;
}

// ------- online-softmax pairwise merge -------
__device__ __forceinline__ void omerge(float& m, float& s, float& a, float& f,
                                       float m2, float s2, float a2, float f2){
  float mn = fmaxf(m, m2);
  float e1 = __expf(m - mn), e2 = __expf(m2 - mn);
  s = s*e1 + s2*e2;
  a = a*e1 + a2*e2;
  m = mn;
  f = fmaxf(f, f2);
}

// ---- MFMA fused fuse-GEMM + att-GEMM + online softmax partials ----
// Block: 64 rows x 512 cols, 512 threads = 8 waves (wave = (mt, half)).
__global__ __launch_bounds__(512) void fuseatt_mfma(
    const float* __restrict__ f1, const float* __restrict__ f2,
    const float* __restrict__ f3, const float* __restrict__ g3,
    const s16* __restrict__ pfw, const float* __restrict__ fb,
    const s16* __restrict__ paw, const float* __restrict__ ab,
    float4* __restrict__ part)
{
  __shared__ __align__(16) char arena[112640];
  s16*   f4s = (s16*)arena;                 // [64][520] bf16 ftr4 tile
  s16*   xs  = (s16*)(arena + 66560);       // [64][360] bf16 input tile
  float4* pb = (float4*)(arena + 66560);    // [4 mt][512 col] partials (aliases xs)
  const int chunk = blockIdx.x;
  const int tid  = threadIdx.x;
  const int lane = tid & 63;
  const int w    = tid >> 6;
  const int mt   = w >> 1;
  const int half = w & 1;
  const int l15  = lane & 15;
  const int lk   = lane >> 4;
  const int n0   = chunk*64;

  // stage xs: gather 64x352 f32 -> bf16
  for (int t = tid; t < 64*352; t += 512){
    int r = t / 352, c = t - r*352;
    int row = n0 + r;
    float v;
    if (c < 32)       v = f1[(size_t)row*32 + c];
    else if (c < 96)  v = f2[(size_t)row*64 + (c-32)];
    else if (c < 224) v = f3[(size_t)row*128 + (c-96)];
    else              v = g3[(size_t)(row>>13)*128 + (c-224)];
    xs[r*360 + c] = (s16)f2bf(v);
  }
  __syncthreads();

  // fuse GEMM: rows mt*16..+15, cols (half*16+ntg)*16..
  {
    const s16* arow = xs + (mt*16 + l15)*360 + lk*8;
    const int rb = mt*16 + lk*4;
    for (int ntg = 0; ntg < 16; ntg += 4){
      const int ntA = half*16 + ntg;
      f32x4 acc0={0,0,0,0}, acc1={0,0,0,0}, acc2={0,0,0,0}, acc3={0,0,0,0};
      for (int kt = 0; kt < 11; ++kt){
        short8v a = *(const short8v*)(arow + kt*32);
        const s16* bp = pfw + (((size_t)kt*32 + ntA)*64 + lane)*8;
        short8v b0 = *(const short8v*)(bp);
        short8v b1 = *(const short8v*)(bp + 512);
        short8v b2 = *(const short8v*)(bp + 1024);
        short8v b3 = *(const short8v*)(bp + 1536);
        acc0 = __builtin_amdgcn_mfma_f32_16x16x32_bf16(a, b0, acc0, 0, 0, 0);
        acc1 = __builtin_amdgcn_mfma_f32_16x16x32_bf16(a, b1, acc1, 0, 0, 0);
        acc2 = __builtin_amdgcn_mfma_f32_16x16x32_bf16(a, b2, acc2, 0, 0, 0);
        acc3 = __builtin_amdgcn_mfma_f32_16x16x32_bf16(a, b3, acc3, 0, 0, 0);
      }
      #define FUSE_EPI(ACC, J) { \
        int col = (ntA + (J))*16 + l15; float bv = fb[col]; \
        f4s[(rb+0)*520 + col] = (s16)f2bf(fmaxf(ACC[0] + bv, 0.f)); \
        f4s[(rb+1)*520 + col] = (s16)f2bf(fmaxf(ACC[1] + bv, 0.f)); \
        f4s[(rb+2)*520 + col] = (s16)f2bf(fmaxf(ACC[2] + bv, 0.f)); \
        f4s[(rb+3)*520 + col] = (s16)f2bf(fmaxf(ACC[3] + bv, 0.f)); }
      FUSE_EPI(acc0, 0) FUSE_EPI(acc1, 1) FUSE_EPI(acc2, 2) FUSE_EPI(acc3, 3)
      #undef FUSE_EPI
    }
  }
  __syncthreads();

  // att GEMM + online softmax partials
  {
    const s16* arow = f4s + (mt*16 + l15)*520 + lk*8;
    const int rb = mt*16 + lk*4;
    for (int ntg = 0; ntg < 16; ntg += 4){
      const int ntA = half*16 + ntg;
      f32x4 acc0={0,0,0,0}, acc1={0,0,0,0}, acc2={0,0,0,0}, acc3={0,0,0,0};
      for (int kt = 0; kt < 16; ++kt){
        short8v a = *(const short8v*)(arow + kt*32);
        const s16* bp = paw + (((size_t)kt*32 + ntA)*64 + lane)*8;
        short8v b0 = *(const short8v*)(bp);
        short8v b1 = *(const short8v*)(bp + 512);
        short8v b2 = *(const short8v*)(bp + 1024);
        short8v b3 = *(const short8v*)(bp + 1536);
        acc0 = __builtin_amdgcn_mfma_f32_16x16x32_bf16(a, b0, acc0, 0, 0, 0);
        acc1 = __builtin_amdgcn_mfma_f32_16x16x32_bf16(a, b1, acc1, 0, 0, 0);
        acc2 = __builtin_amdgcn_mfma_f32_16x16x32_bf16(a, b2, acc2, 0, 0, 0);
        acc3 = __builtin_amdgcn_mfma_f32_16x16x32_bf16(a, b3, acc3, 0, 0, 0);
      }
      #define ATT_EPI(ACC, J) { \
        int col = (ntA + (J))*16 + l15; float lb = ab[col]; \
        float m_ = -INFINITY, s_ = 0.f, a_ = 0.f, fx_ = 0.f; \
        _Pragma("unroll") \
        for (int r = 0; r < 4; ++r){ \
          float lv = ACC[r] + lb; \
          float x  = bf2f((unsigned short)f4s[(rb+r)*520 + col]); \
          float mn = fmaxf(m_, lv); \
          float e0 = __expf(m_ - mn), e1 = __expf(lv - mn); \
          s_ = s_*e0 + e1; a_ = a_*e0 + x*e1; m_ = mn; fx_ = fmaxf(fx_, x); \
        } \
        { float om = __shfl_xor(m_,16), os = __shfl_xor(s_,16), oa = __shfl_xor(a_,16), of = __shfl_xor(fx_,16); \
          omerge(m_, s_, a_, fx_, om, os, oa, of); } \
        { float om = __shfl_xor(m_,32), os = __shfl_xor(s_,32), oa = __shfl_xor(a_,32), of = __shfl_xor(fx_,32); \
          omerge(m_, s_, a_, fx_, om, os, oa, of); } \
        if (lk == 0) pb[mt*512 + col] = make_float4(m_, s_, a_, fx_); }
      ATT_EPI(acc0, 0) ATT_EPI(acc1, 1) ATT_EPI(acc2, 2) ATT_EPI(acc3, 3)
      #undef ATT_EPI
    }
  }
  __syncthreads();

  // merge the 4 m-tile partials per column, write global
  {
    float4 p0 = pb[tid], p1 = pb[512 + tid], p2 = pb[1024 + tid], p3 = pb[1536 + tid];
    float m_ = p0.x, s_ = p0.y, a_ = p0.z, f_ = p0.w;
    omerge(m_, s_, a_, f_, p1.x, p1.y, p1.z, p1.w);
    omerge(m_, s_, a_, f_, p2.x, p2.y, p2.z, p2.w);
    omerge(m_, s_, a_, f_, p3.x, p3.y, p3.z, p3.w);
    part[(size_t)chunk*512 + tid] = make_float4(m_, s_, a_, f_);
  }
}

// ---- scalar fallback fuseatt (round-6 version) ----
__global__ __launch_bounds__(512) void fuseatt_kernel(
    const float* __restrict__ f1, const float* __restrict__ f2,
    const float* __restrict__ f3, const float* __restrict__ g3,
    const float* __restrict__ fw, const float* __restrict__ fb,
    const float* __restrict__ aw, const float* __restrict__ ab,
    float4* __restrict__ part)
{
  __shared__ float xs[352*16];
  __shared__ float f4[16*512];
  const int chunk = blockIdx.x;
  const int tid = threadIdx.x;
  float m=-INFINITY, s=0.f, a=0.f, fx=0.f;
  const float4* xs4 = (const float4*)xs;
  const float4* f4r = (const float4*)f4;
  for (int sub=0; sub<4; ++sub){
    __syncthreads();
    const int n0 = chunk*64 + sub*16;
    for (int t = tid; t < 16*352; t += 512){
      int c = t >> 4, p = t & 15;
      int row = n0 + p;
      float v;
      if (c < 32)       v = f1[(size_t)row*32 + c];
      else if (c < 96)  v = f2[(size_t)row*64 + (c-32)];
      else if (c < 224) v = f3[(size_t)row*128 + (c-96)];
      else              v = g3[(size_t)(row>>13)*128 + (c-224)];
      xs[c*16 + p] = v;
    }
    __syncthreads();
    {
      float acc[16];
      #pragma unroll
      for (int r=0;r<16;++r) acc[r]=0.f;
      for (int k=0;k<352;k+=4){
        float w0 = fw[(size_t)(k+0)*512 + tid];
        float w1 = fw[(size_t)(k+1)*512 + tid];
        float w2 = fw[(size_t)(k+2)*512 + tid];
        float w3 = fw[(size_t)(k+3)*512 + tid];
        #pragma unroll
        for (int q=0;q<4;++q){
          float4 x0 = xs4[(k+0)*4 + q];
          float4 x1 = xs4[(k+1)*4 + q];
          float4 x2 = xs4[(k+2)*4 + q];
          float4 x3 = xs4[(k+3)*4 + q];
          acc[q*4+0] += x0.x*w0 + x1.x*w1 + x2.x*w2 + x3.x*w3;
          acc[q*4+1] += x0.y*w0 + x1.y*w1 + x2.y*w2 + x3.y*w3;
          acc[q*4+2] += x0.z*w0 + x1.z*w1 + x2.z*w2 + x3.z*w3;
          acc[q*4+3] += x0.w*w0 + x1.w*w1 + x2.w*w2 + x3.w*w3;
        }
      }
      float bv = fb[tid];
      #pragma unroll
      for (int r=0;r<16;++r) f4[r*512 + tid] = fmaxf(acc[r] + bv, 0.f);
    }
    __syncthreads();
    {
      float acc[16];
      #pragma unroll
      for (int r=0;r<16;++r) acc[r]=0.f;
      #pragma unroll 2
      for (int k4=0;k4<128;++k4){
        int k = k4*4;
        float w0 = aw[(size_t)(k+0)*512 + tid];
        float w1 = aw[(size_t)(k+1)*512 + tid];
        float w2 = aw[(size_t)(k+2)*512 + tid];
        float w3 = aw[(size_t)(k+3)*512 + tid];
        #pragma unroll
        for (int r=0;r<16;++r){
          float4 fv = f4r[r*128 + k4];
          acc[r] += fv.x*w0 + fv.y*w1 + fv.z*w2 + fv.w*w3;
        }
      }
      float lb = ab[tid];
      #pragma unroll
      for (int r=0;r<16;++r){
        float l = acc[r] + lb;
        float x = f4[r*512 + tid];
        float mn = fmaxf(m, l);
        float e0 = __expf(m - mn);
        float e1 = __expf(l - mn);
        s = s*e0 + e1;
        a = a*e0 + x*e1;
        m = mn;
        fx = fmaxf(fx, x);
      }
    }
  }
  part[(size_t)chunk*512 + tid] = make_float4(m, s, a, fx);
}

__global__ __launch_bounds__(256) void attmerge_kernel(const float4* __restrict__ part, float* __restrict__ feat){
  int t = blockIdx.x*256 + threadIdx.x;
  if (t >= BB*512) return;
  int b = t >> 9, f = t & 511;
  float m=-INFINITY, s=0.f, a=0.f, fx=0.f;
  for (int c=0;c<128;++c){
    float4 p = part[((size_t)(b*128 + c))*512 + f];
    float mn = fmaxf(m, p.x);
    float e0 = __expf(m - mn), e1 = __expf(p.x - mn);
    s = s*e0 + p.y*e1;
    a = a*e0 + p.z*e1;
    m = mn;
    fx = fmaxf(fx, p.w);
  }
  feat[(size_t)b*1024 + f] = fx;
  feat[(size_t)b*1024 + 512 + f] = a / s;
}

// ------------- head MLP (N=2 rows) -------------
__global__ __launch_bounds__(256) void head_kernel(
    const float* __restrict__ X, const float* __restrict__ W, const float* __restrict__ bias,
    float* __restrict__ Y, int K, int J, int relu_flag)
{
  int j = blockIdx.x*256 + threadIdx.x;
  if (j >= J) return;
  float bv = bias[j];
  float a0 = bv, a1 = bv;
  for (int k=0;k<K;++k){
    float w = W[(size_t)k*J + j];
    a0 += X[k]   * w;
    a1 += X[K+k] * w;
  }
  if (relu_flag){ a0 = fmaxf(a0,0.f); a1 = fmaxf(a1,0.f); }
  Y[j] = a0; Y[J+j] = a1;
}

extern "C" void kernel_launch(void* const* d_in, const int* in_sizes, int n_in,
                              void* d_out, int out_size, void* d_ws, size_t ws_size,
                              hipStream_t stream)
{
  const float* pts    = (const float*)d_in[0];
  const float* na1w1  = (const float*)d_in[1];
  const float* na1b1  = (const float*)d_in[2];
  const float* na1w2  = (const float*)d_in[3];
  const float* na1b2  = (const float*)d_in[4];
  const float* na2w   = (const float*)d_in[5];
  const float* na2b   = (const float*)d_in[6];
  const float* na3w   = (const float*)d_in[7];
  const float* na3b   = (const float*)d_in[8];
  const float* r1aw   = (const float*)d_in[9];
  const float* r1ab   = (const float*)d_in[10];
  const float* r1bw   = (const float*)d_in[11];
  const float* r1bb   = (const float*)d_in[12];
  const float* r1sw   = (const float*)d_in[13];
  const float* r1sb   = (const float*)d_in[14];
  const float* r2aw   = (const float*)d_in[15];
  const float* r2ab   = (const float*)d_in[16];
  const float* r2bw   = (const float*)d_in[17];
  const float* r2bb   = (const float*)d_in[18];
  const float* r2sw   = (const float*)d_in[19];
  const float* r2sb   = (const float*)d_in[20];
  const float* fusew  = (const float*)d_in[21];
  const float* fuseb  = (const float*)d_in[22];
  const float* attw   = (const float*)d_in[23];
  const float* attb   = (const float*)d_in[24];
  const float* fc1w   = (const float*)d_in[25];
  const float* fc1b   = (const float*)d_in[26];
  const float* fc2w   = (const float*)d_in[27];
  const float* fc2b   = (const float*)d_in[28];
  const float* fc3w   = (const float*)d_in[29];
  const float* fc3b   = (const float*)d_in[30];

  if (n_in < 31) return;
  if (in_sizes[0] != NPTS*3) return;
  if (in_sizes[21] != 352*512) return;
  if (in_sizes[29] != 1024*1024) return;

  // Workspace layout (float offsets).
  const size_t o_ftr1 = 0;
  const size_t o_ftr2 = 524288;
  const size_t o_ftr3 = 1572864;
  const size_t o_knn  = 1572864;
  const size_t o_part = 3670016;
  const size_t o_g2   = 4194304;
  const size_t o_g3   = 4194432;
  const size_t o_feat = 4194688;
  const size_t o_h1   = 4196736;
  const size_t o_h2   = 4197760;        // end 4199808
  const size_t o_pfw  = 4199808;        // 352*512 bf16 = 90112 floats
  const size_t o_paw  = o_pfw + 90112;  // 512*512 bf16 = 131072 floats -> end 4420992
  const size_t base_bytes = 4199808ull * 4ull;
  const size_t mfma_bytes = 4420992ull * 4ull;
  if (ws_size < base_bytes) return;
  const bool use_mfma = (ws_size >= mfma_bytes);

  float* ws = (float*)d_ws;
  float*  ftr1 = ws + o_ftr1;
  float*  ftr2 = ws + o_ftr2;
  float*  ftr3 = ws + o_ftr3;
  int*    knn  = (int*)(ws + o_knn);
  float4* part = (float4*)(ws + o_part);
  float*  g2   = ws + o_g2;
  float*  g3   = ws + o_g3;
  float*  feat = ws + o_feat;
  float*  h1   = ws + o_h1;
  float*  h2   = ws + o_h2;
  s16*    pfw  = (s16*)(ws + o_pfw);
  s16*    paw  = (s16*)(ws + o_paw);

  zero_kernel<<<2, 256, 0, stream>>>(g2, 384);
  if (use_mfma){
    packw_kernel<<<11*32, 64, 0, stream>>>(fusew, pfw);
    packw_kernel<<<16*32, 64, 0, stream>>>(attw, paw);
  }
  knn_kernel<<<NPTS, 64, 0, stream>>>(pts, knn);
  nbr_kernel<<<NPTS*16/256, 256, 0, stream>>>(pts, knn, na1w1, na1b1, na1w2, na1b2,
                                              na2w, na2b, na3w, na3b, ftr1);
  resblock_kernel<32,64><<<NPTS/16, 256, 0, stream>>>(ftr1, 32, nullptr, 0,
                                                      r1aw, r1ab, r1bw, r1bb, r1sw, r1sb, ftr2);
  colmax_kernel<<<dim3(32,2), 256, 0, stream>>>(ftr2, g2, 64);
  resblock_kernel<128,128><<<NPTS/16, 256, 0, stream>>>(ftr2, 64, g2, 1,
                                                        r2aw, r2ab, r2bw, r2bb, r2sw, r2sb, ftr3);
  colmax_kernel<<<dim3(32,2), 256, 0, stream>>>(ftr3, g3, 128);
  if (use_mfma){
    fuseatt_mfma<<<NPTS/64, 512, 0, stream>>>(ftr1, ftr2, ftr3, g3,
                                              pfw, fuseb, paw, attb, part);
  } else {
    fuseatt_kernel<<<NPTS/64, 512, 0, stream>>>(ftr1, ftr2, ftr3, g3,
                                                fusew, fuseb, attw, attb, part);
  }
  attmerge_kernel<<<4, 256, 0, stream>>>(part, feat);
  head_kernel<<<2, 256, 0, stream>>>(feat, fc1w, fc1b, h1, 1024, 512, 1);
  head_kernel<<<4, 256, 0, stream>>>(h1,   fc2w, fc2b, h2, 512, 1024, 1);
  head_kernel<<<4, 256, 0, stream>>>(h2,   fc3w, fc3b, (float*)d_out, 1024, 1024, 0);
}

// Round 8
// 501.040 us; speedup vs baseline: 2.8733x; 2.1640x over previous
//
#include <hip/hip_runtime.h>
#include <math.h>

#define BB 2
#define NN 8192
#define NPTS (BB*NN)

typedef unsigned long long u64;
typedef short s16;
typedef __attribute__((ext_vector_type(8))) short short8v;
typedef __attribute__((ext_vector_type(4))) float f32x4;

__device__ __forceinline__ unsigned short f2bf(float v){
  unsigned u = __float_as_uint(v);
  return (unsigned short)((u + 0x7FFFu + ((u >> 16) & 1u)) >> 16);
}
__device__ __forceinline__ float bf2f(unsigned short h){
  return __uint_as_float(((unsigned)h) << 16);
}

// ---------------- zero init (g2/g3 atomic-max targets) ----------------
__global__ __launch_bounds__(256) void zero_kernel(float* p, int n){
  int i = blockIdx.x*256 + threadIdx.x;
  if (i < n) p[i] = 0.f;
}

// ---------------- KNN helpers: branchless bitonic primitives ----------------
__device__ __forceinline__ void ce(u64& a, u64& b){
  u64 lo = a < b ? a : b;
  u64 hi = a < b ? b : a;
  a = lo; b = hi;
}

__device__ __forceinline__ void bclean16(u64 e[16]){
  #pragma unroll
  for (int i=0;i<8;++i) ce(e[i], e[i+8]);
  #pragma unroll
  for (int g=0; g<2; ++g){
    #pragma unroll
    for (int i=0;i<4;++i) ce(e[g*8+i], e[g*8+i+4]);
  }
  #pragma unroll
  for (int g=0; g<4; ++g){
    #pragma unroll
    for (int i=0;i<2;++i) ce(e[g*4+i], e[g*4+i+2]);
  }
  #pragma unroll
  for (int g=0; g<8; ++g) ce(e[g*2], e[g*2+1]);
}

__device__ __forceinline__ void merge_keep16(u64 e[16], int maskXor){
  u64 p[16];
  #pragma unroll
  for (int i=0;i<16;++i) p[i] = __shfl_xor(e[i], maskXor);
  #pragma unroll
  for (int i=0;i<16;++i){ u64 o = p[15-i]; e[i] = e[i] < o ? e[i] : o; }
  bclean16(e);
}

// ---------------- KNN: one wave per point ----------------
__global__ __launch_bounds__(64) void knn_kernel(const float* __restrict__ pts, int* __restrict__ knn){
  const int point = blockIdx.x;
  const int b = point >> 13;
  const int n = point & (NN-1);
  const int lane = threadIdx.x;
  const float* pb = pts + (size_t)b*NN*3;
  const float px = pb[(size_t)n*3+0];
  const float py = pb[(size_t)n*3+1];
  const float pz = pb[(size_t)n*3+2];

  u64 k0=~0ull, k1=~0ull, k2=~0ull, k3=~0ull;
  #pragma unroll 4
  for (int t=0; t<128; ++t){
    int m = lane + (t<<6);
    float dx = pb[(size_t)m*3+0] - px;
    float dy = pb[(size_t)m*3+1] - py;
    float dz = pb[(size_t)m*3+2] - pz;
    float dist = dx*dx + dy*dy + dz*dz;
    u64 c = ((u64)__float_as_uint(dist) << 32) | (unsigned)m;
    c = (m == n) ? ~0ull : c;
    bool l3 = c < k3, l2 = c < k2, l1 = c < k1, l0 = c < k0;
    k3 = l3 ? (l2 ? k2 : c) : k3;
    k2 = l2 ? (l1 ? k1 : c) : k2;
    k1 = l1 ? (l0 ? k0 : c) : k1;
    k0 = l0 ? c : k0;
  }
  const u64 k3s = k3;

  u64 e[16];
  {
    u64 p0=__shfl_xor(k0,1), p1=__shfl_xor(k1,1), p2=__shfl_xor(k2,1), p3=__shfl_xor(k3,1);
    e[0]=k0; e[1]=k1; e[2]=k2; e[3]=k3;
    e[4]=p3; e[5]=p2; e[6]=p1; e[7]=p0;
    ce(e[0],e[4]); ce(e[1],e[5]); ce(e[2],e[6]); ce(e[3],e[7]);
    ce(e[0],e[2]); ce(e[1],e[3]); ce(e[4],e[6]); ce(e[5],e[7]);
    ce(e[0],e[1]); ce(e[2],e[3]); ce(e[4],e[5]); ce(e[6],e[7]);
  }
  {
    u64 p[8];
    #pragma unroll
    for (int i=0;i<8;++i) p[i] = __shfl_xor(e[i], 2);
    #pragma unroll
    for (int i=0;i<8;++i) e[8+i] = p[7-i];
    bclean16(e);
  }
  merge_keep16(e, 4);
  merge_keep16(e, 8);
  merge_keep16(e, 16);
  merge_keep16(e, 32);

  const u64 T = e[15];
  u64 bal = __ballot(k3s < T);
  if (bal == 0){
    if (lane == 0){
      #pragma unroll
      for (int i=0;i<16;++i) knn[(size_t)point*16 + i] = (int)(unsigned)(e[i] & 0xffffffffu);
    }
    return;
  }

  float d[16]; int id[16];
  #pragma unroll
  for (int j=0;j<16;++j){ d[j]=INFINITY; id[j]=0x7fffffff; }
  for (int m = lane; m < NN; m += 64){
    if (m == n) continue;
    float dx = pb[(size_t)m*3+0] - px;
    float dy = pb[(size_t)m*3+1] - py;
    float dz = pb[(size_t)m*3+2] - pz;
    float dist = dx*dx + dy*dy + dz*dz;
    if (dist < d[15] || (dist == d[15] && m < id[15])){
      float cd = dist; int ci = m;
      #pragma unroll
      for (int j=0;j<16;++j){
        bool sw = (cd < d[j]) || (cd == d[j] && ci < id[j]);
        float td = sw ? d[j] : cd; int ti = sw ? id[j] : ci;
        d[j]  = sw ? cd : d[j];
        id[j] = sw ? ci : id[j];
        cd = td; ci = ti;
      }
    }
  }
  for (int r=0; r<16; ++r){
    float bd = d[0]; int bi = id[0];
    for (int off=32; off>=1; off>>=1){
      float od = __shfl_xor(bd, off);
      int   oi = __shfl_xor(bi, off);
      bool take = (od < bd) || (od == bd && oi < bi);
      bd = take ? od : bd; bi = take ? oi : bi;
    }
    if (d[0] == bd && id[0] == bi){
      knn[(size_t)point*16 + r] = bi;
      #pragma unroll
      for (int j=0;j<15;++j){ d[j]=d[j+1]; id[j]=id[j+1]; }
      d[15]=INFINITY; id[15]=0x7fffffff;
    }
  }
}

// ------------- neighbor MLP + pool + ftr_1 (thread = point*16+k) -------------
__global__ __launch_bounds__(256) void nbr_kernel(
    const float* __restrict__ pts, const int* __restrict__ knn,
    const float* __restrict__ w1, const float* __restrict__ b1,
    const float* __restrict__ w2, const float* __restrict__ b2,
    const float* __restrict__ wp, const float* __restrict__ bp,
    const float* __restrict__ w3, const float* __restrict__ b3,
    float* __restrict__ ftr1)
{
  __shared__ float sw1[7*16], sb1[16], sw2[16*32], sb2[32], swp[3*32], sbp[32], sw3[64*32], sb3[32];
  for (int t = threadIdx.x; t < 7*16;  t += 256) sw1[t] = w1[t];
  for (int t = threadIdx.x; t < 16;    t += 256) sb1[t] = b1[t];
  for (int t = threadIdx.x; t < 16*32; t += 256) sw2[t] = w2[t];
  for (int t = threadIdx.x; t < 32;    t += 256) sb2[t] = b2[t];
  for (int t = threadIdx.x; t < 3*32;  t += 256) swp[t] = wp[t];
  for (int t = threadIdx.x; t < 32;    t += 256) sbp[t] = bp[t];
  for (int t = threadIdx.x; t < 64*32; t += 256) sw3[t] = w3[t];
  for (int t = threadIdx.x; t < 32;    t += 256) sb3[t] = b3[t];
  __syncthreads();
  int gt = blockIdx.x*256 + threadIdx.x;
  int point = gt >> 4;
  int k = gt & 15;
  int b = point >> 13;
  float ax = pts[(size_t)point*3+0];
  float ay = pts[(size_t)point*3+1];
  float az = pts[(size_t)point*3+2];
  int idx = knn[(size_t)point*16 + k] & (NN-1);
  size_t nb = ((size_t)b*NN + idx)*3;
  float rx = pts[nb+0] - ax;
  float ry = pts[nb+1] - ay;
  float rz = pts[nb+2] - az;
  float dd = sqrtf(rx*rx + ry*ry + rz*rz + 1e-8f);
  float in7[7] = {ax, ay, az, rx, ry, rz, dd};
  float h16[16];
  #pragma unroll
  for (int j=0;j<16;++j){
    float a = sb1[j];
    #pragma unroll
    for (int c=0;c<7;++c) a += in7[c]*sw1[c*16+j];
    h16[j] = fmaxf(a, 0.f);
  }
  float h32[32];
  #pragma unroll
  for (int j=0;j<32;++j){
    float a = sb2[j];
    #pragma unroll
    for (int c=0;c<16;++c) a += h16[c]*sw2[c*32+j];
    h32[j] = fmaxf(a, 0.f);
  }
  #pragma unroll
  for (int j=0;j<32;++j){
    h32[j] = fmaxf(h32[j], __shfl_xor(h32[j], 8));
    h32[j] = fmaxf(h32[j], __shfl_xor(h32[j], 4));
    h32[j] = fmaxf(h32[j], __shfl_xor(h32[j], 2));
    h32[j] = fmaxf(h32[j], __shfl_xor(h32[j], 1));
  }
  if (k == 0){
    float lift[32];
    #pragma unroll
    for (int j=0;j<32;++j){
      float a = sbp[j] + ax*swp[0*32+j] + ay*swp[1*32+j] + az*swp[2*32+j];
      lift[j] = fmaxf(a, 0.f);
    }
    #pragma unroll
    for (int j=0;j<32;++j){
      float a = sb3[j];
      #pragma unroll
      for (int c=0;c<32;++c) a += lift[c]*sw3[c*32+j];
      #pragma unroll
      for (int c=0;c<32;++c) a += h32[c]*sw3[(32+c)*32+j];
      ftr1[(size_t)point*32 + j] = fmaxf(a, 0.f);
    }
  }
}

// ------- fused residual SMLP (unchanged) -------
template<int KIN, int JM>
__global__ __launch_bounds__(256) void resblock_kernel(
    const float* __restrict__ s0, int w0,
    const float* __restrict__ s1, int bc1,
    const float* __restrict__ wa, const float* __restrict__ ba,
    const float* __restrict__ wb, const float* __restrict__ bb,
    const float* __restrict__ wsk, const float* __restrict__ bs,
    float* __restrict__ Y)
{
  __shared__ float xs[KIN*16];
  __shared__ float as_[JM*16];
  const int n0 = blockIdx.x * 16;
  for (int t = threadIdx.x; t < 16*KIN; t += 256){
    int p = t / KIN, c = t - p*KIN;
    int row = n0 + p;
    float v = (c < w0) ? s0[(size_t)row*w0 + c]
                       : s1[(size_t)(bc1 ? (row>>13) : row)*(KIN-w0) + (c-w0)];
    xs[c*16 + p] = v;
  }
  __syncthreads();
  constexpr int ROWS = (JM == 64) ? 4 : 8;
  const int j  = threadIdx.x % JM;
  const int p0 = (threadIdx.x / JM) * ROWS;
  const float4* xs4 = (const float4*)xs;
  {
    float acc[ROWS];
    #pragma unroll
    for (int r=0;r<ROWS;++r) acc[r]=0.f;
    for (int k=0;k<KIN;++k){
      float w = wa[(size_t)k*JM + j];
      #pragma unroll
      for (int q=0;q<ROWS/4;++q){
        float4 xv = xs4[k*4 + (p0>>2) + q];
        acc[q*4+0] += xv.x*w; acc[q*4+1] += xv.y*w;
        acc[q*4+2] += xv.z*w; acc[q*4+3] += xv.w*w;
      }
    }
    float bv = ba[j];
    #pragma unroll
    for (int r=0;r<ROWS;++r) as_[j*16 + p0 + r] = fmaxf(acc[r] + bv, 0.f);
  }
  __syncthreads();
  {
    const float4* as4 = (const float4*)as_;
    float acc[ROWS];
    #pragma unroll
    for (int r=0;r<ROWS;++r) acc[r]=0.f;
    for (int k=0;k<JM;++k){
      float w = wb[(size_t)k*JM + j];
      #pragma unroll
      for (int q=0;q<ROWS/4;++q){
        float4 xv = as4[k*4 + (p0>>2) + q];
        acc[q*4+0] += xv.x*w; acc[q*4+1] += xv.y*w;
        acc[q*4+2] += xv.z*w; acc[q*4+3] += xv.w*w;
      }
    }
    for (int k=0;k<KIN;++k){
      float w = wsk[(size_t)k*JM + j];
      #pragma unroll
      for (int q=0;q<ROWS/4;++q){
        float4 xv = xs4[k*4 + (p0>>2) + q];
        acc[q*4+0] += xv.x*w; acc[q*4+1] += xv.y*w;
        acc[q*4+2] += xv.z*w; acc[q*4+3] += xv.w*w;
      }
    }
    float bv = bb[j] + bs[j];
    #pragma unroll
    for (int r=0;r<ROWS;++r)
      Y[(size_t)(n0 + p0 + r)*JM + j] = fmaxf(acc[r] + bv, 0.f);
  }
}

// ------------- column max over N per batch -------------
__global__ __launch_bounds__(256) void colmax_kernel(const float* __restrict__ X, float* __restrict__ out, int J){
  int b  = blockIdx.y;
  int n0 = blockIdx.x * 256;
  int f  = threadIdx.x % J;
  int r0 = threadIdx.x / J;
  int step = 256 / J;
  float vm = 0.f;
  for (int n = n0 + r0; n < n0 + 256; n += step)
    vm = fmaxf(vm, X[((size_t)b*NN + n)*J + f]);
  atomicMax((int*)&out[b*J + f], __float_as_int(vm));
}

// ------- weight pack: W[K,512] f32 -> bf16 MFMA B-fragment order -------
__global__ __launch_bounds__(64) void packw_kernel(const float* __restrict__ W, s16* __restrict__ out){
  int kt = blockIdx.x >> 5, nt = blockIdx.x & 31;
  int lane = threadIdx.x;
  int k0 = kt*32 + ((lane>>4)<<3);
  int n  = nt*16 + (lane & 15);
  s16 v[8];
  #pragma unroll
  for (int i=0;i<8;++i) v[i] = (s16)f2bf(W[(size_t)(k0+i)*512 + n]);
  *(short8v*)(out + (((size_t)blockIdx.x)*64 + lane)*8) = *(short8v*)v;
}

// ------- online-softmax pairwise merge -------
__device__ __forceinline__ void omerge(float& m, float& s, float& a, float& f,
                                       float m2, float s2, float a2, float f2){
  float mn = fmaxf(m, m2);
  float e1 = __expf(m - mn), e2 = __expf(m2 - mn);
  s = s*e1 + s2*e2;
  a = a*e1 + a2*e2;
  m = mn;
  f = fmaxf(f, f2);
}

// ---- MFMA fused fuse-GEMM + att-GEMM + online softmax partials ----
__global__ __launch_bounds__(512) void fuseatt_mfma(
    const float* __restrict__ f1, const float* __restrict__ f2,
    const float* __restrict__ f3, const float* __restrict__ g3,
    const s16* __restrict__ pfw, const float* __restrict__ fb,
    const s16* __restrict__ paw, const float* __restrict__ ab,
    float4* __restrict__ part)
{
  __shared__ __align__(16) char arena[112640];
  s16*   f4s = (s16*)arena;                 // [64][520] bf16 ftr4 tile
  s16*   xs  = (s16*)(arena + 66560);       // [64][360] bf16 input tile
  float4* pb = (float4*)(arena + 66560);    // [4 mt][512 col] partials (aliases xs)
  const int chunk = blockIdx.x;
  const int tid  = threadIdx.x;
  const int lane = tid & 63;
  const int w    = tid >> 6;
  const int mt   = w >> 1;
  const int half = w & 1;
  const int l15  = lane & 15;
  const int lk   = lane >> 4;
  const int n0   = chunk*64;

  for (int t = tid; t < 64*352; t += 512){
    int r = t / 352, c = t - r*352;
    int row = n0 + r;
    float v;
    if (c < 32)       v = f1[(size_t)row*32 + c];
    else if (c < 96)  v = f2[(size_t)row*64 + (c-32)];
    else if (c < 224) v = f3[(size_t)row*128 + (c-96)];
    else              v = g3[(size_t)(row>>13)*128 + (c-224)];
    xs[r*360 + c] = (s16)f2bf(v);
  }
  __syncthreads();

  {
    const s16* arow = xs + (mt*16 + l15)*360 + lk*8;
    const int rb = mt*16 + lk*4;
    for (int ntg = 0; ntg < 16; ntg += 4){
      const int ntA = half*16 + ntg;
      f32x4 acc0={0,0,0,0}, acc1={0,0,0,0}, acc2={0,0,0,0}, acc3={0,0,0,0};
      for (int kt = 0; kt < 11; ++kt){
        short8v a = *(const short8v*)(arow + kt*32);
        const s16* bp = pfw + (((size_t)kt*32 + ntA)*64 + lane)*8;
        short8v b0 = *(const short8v*)(bp);
        short8v b1 = *(const short8v*)(bp + 512);
        short8v b2 = *(const short8v*)(bp + 1024);
        short8v b3 = *(const short8v*)(bp + 1536);
        acc0 = __builtin_amdgcn_mfma_f32_16x16x32_bf16(a, b0, acc0, 0, 0, 0);
        acc1 = __builtin_amdgcn_mfma_f32_16x16x32_bf16(a, b1, acc1, 0, 0, 0);
        acc2 = __builtin_amdgcn_mfma_f32_16x16x32_bf16(a, b2, acc2, 0, 0, 0);
        acc3 = __builtin_amdgcn_mfma_f32_16x16x32_bf16(a, b3, acc3, 0, 0, 0);
      }
      #define FUSE_EPI(ACC, J) { \
        int col = (ntA + (J))*16 + l15; float bv = fb[col]; \
        f4s[(rb+0)*520 + col] = (s16)f2bf(fmaxf(ACC[0] + bv, 0.f)); \
        f4s[(rb+1)*520 + col] = (s16)f2bf(fmaxf(ACC[1] + bv, 0.f)); \
        f4s[(rb+2)*520 + col] = (s16)f2bf(fmaxf(ACC[2] + bv, 0.f)); \
        f4s[(rb+3)*520 + col] = (s16)f2bf(fmaxf(ACC[3] + bv, 0.f)); }
      FUSE_EPI(acc0, 0) FUSE_EPI(acc1, 1) FUSE_EPI(acc2, 2) FUSE_EPI(acc3, 3)
      #undef FUSE_EPI
    }
  }
  __syncthreads();

  {
    const s16* arow = f4s + (mt*16 + l15)*520 + lk*8;
    const int rb = mt*16 + lk*4;
    for (int ntg = 0; ntg < 16; ntg += 4){
      const int ntA = half*16 + ntg;
      f32x4 acc0={0,0,0,0}, acc1={0,0,0,0}, acc2={0,0,0,0}, acc3={0,0,0,0};
      for (int kt = 0; kt < 16; ++kt){
        short8v a = *(const short8v*)(arow + kt*32);
        const s16* bp = paw + (((size_t)kt*32 + ntA)*64 + lane)*8;
        short8v b0 = *(const short8v*)(bp);
        short8v b1 = *(const short8v*)(bp + 512);
        short8v b2 = *(const short8v*)(bp + 1024);
        short8v b3 = *(const short8v*)(bp + 1536);
        acc0 = __builtin_amdgcn_mfma_f32_16x16x32_bf16(a, b0, acc0, 0, 0, 0);
        acc1 = __builtin_amdgcn_mfma_f32_16x16x32_bf16(a, b1, acc1, 0, 0, 0);
        acc2 = __builtin_amdgcn_mfma_f32_16x16x32_bf16(a, b2, acc2, 0, 0, 0);
        acc3 = __builtin_amdgcn_mfma_f32_16x16x32_bf16(a, b3, acc3, 0, 0, 0);
      }
      #define ATT_EPI(ACC, J) { \
        int col = (ntA + (J))*16 + l15; float lb = ab[col]; \
        float m_ = -INFINITY, s_ = 0.f, a_ = 0.f, fx_ = 0.f; \
        _Pragma("unroll") \
        for (int r = 0; r < 4; ++r){ \
          float lv = ACC[r] + lb; \
          float x  = bf2f((unsigned short)f4s[(rb+r)*520 + col]); \
          float mn = fmaxf(m_, lv); \
          float e0 = __expf(m_ - mn), e1 = __expf(lv - mn); \
          s_ = s_*e0 + e1; a_ = a_*e0 + x*e1; m_ = mn; fx_ = fmaxf(fx_, x); \
        } \
        { float om = __shfl_xor(m_,16), os = __shfl_xor(s_,16), oa = __shfl_xor(a_,16), of = __shfl_xor(fx_,16); \
          omerge(m_, s_, a_, fx_, om, os, oa, of); } \
        { float om = __shfl_xor(m_,32), os = __shfl_xor(s_,32), oa = __shfl_xor(a_,32), of = __shfl_xor(fx_,32); \
          omerge(m_, s_, a_, fx_, om, os, oa, of); } \
        if (lk == 0) pb[mt*512 + col] = make_float4(m_, s_, a_, fx_); }
      ATT_EPI(acc0, 0) ATT_EPI(acc1, 1) ATT_EPI(acc2, 2) ATT_EPI(acc3, 3)
      #undef ATT_EPI
    }
  }
  __syncthreads();

  {
    float4 p0 = pb[tid], p1 = pb[512 + tid], p2 = pb[1024 + tid], p3 = pb[1536 + tid];
    float m_ = p0.x, s_ = p0.y, a_ = p0.z, f_ = p0.w;
    omerge(m_, s_, a_, f_, p1.x, p1.y, p1.z, p1.w);
    omerge(m_, s_, a_, f_, p2.x, p2.y, p2.z, p2.w);
    omerge(m_, s_, a_, f_, p3.x, p3.y, p3.z, p3.w);
    part[(size_t)chunk*512 + tid] = make_float4(m_, s_, a_, f_);
  }
}

// ---- scalar fallback fuseatt ----
__global__ __launch_bounds__(512) void fuseatt_kernel(
    const float* __restrict__ f1, const float* __restrict__ f2,
    const float* __restrict__ f3, const float* __restrict__ g3,
    const float* __restrict__ fw, const float* __restrict__ fb,
    const float* __restrict__ aw, const float* __restrict__ ab,
    float4* __restrict__ part)
{
  __shared__ float xs[352*16];
  __shared__ float f4[16*512];
  const int chunk = blockIdx.x;
  const int tid = threadIdx.x;
  float m=-INFINITY, s=0.f, a=0.f, fx=0.f;
  const float4* xs4 = (const float4*)xs;
  const float4* f4r = (const float4*)f4;
  for (int sub=0; sub<4; ++sub){
    __syncthreads();
    const int n0 = chunk*64 + sub*16;
    for (int t = tid; t < 16*352; t += 512){
      int c = t >> 4, p = t & 15;
      int row = n0 + p;
      float v;
      if (c < 32)       v = f1[(size_t)row*32 + c];
      else if (c < 96)  v = f2[(size_t)row*64 + (c-32)];
      else if (c < 224) v = f3[(size_t)row*128 + (c-96)];
      else              v = g3[(size_t)(row>>13)*128 + (c-224)];
      xs[c*16 + p] = v;
    }
    __syncthreads();
    {
      float acc[16];
      #pragma unroll
      for (int r=0;r<16;++r) acc[r]=0.f;
      for (int k=0;k<352;k+=4){
        float w0 = fw[(size_t)(k+0)*512 + tid];
        float w1 = fw[(size_t)(k+1)*512 + tid];
        float w2 = fw[(size_t)(k+2)*512 + tid];
        float w3 = fw[(size_t)(k+3)*512 + tid];
        #pragma unroll
        for (int q=0;q<4;++q){
          float4 x0 = xs4[(k+0)*4 + q];
          float4 x1 = xs4[(k+1)*4 + q];
          float4 x2 = xs4[(k+2)*4 + q];
          float4 x3 = xs4[(k+3)*4 + q];
          acc[q*4+0] += x0.x*w0 + x1.x*w1 + x2.x*w2 + x3.x*w3;
          acc[q*4+1] += x0.y*w0 + x1.y*w1 + x2.y*w2 + x3.y*w3;
          acc[q*4+2] += x0.z*w0 + x1.z*w1 + x2.z*w2 + x3.z*w3;
          acc[q*4+3] += x0.w*w0 + x1.w*w1 + x2.w*w2 + x3.w*w3;
        }
      }
      float bv = fb[tid];
      #pragma unroll
      for (int r=0;r<16;++r) f4[r*512 + tid] = fmaxf(acc[r] + bv, 0.f);
    }
    __syncthreads();
    {
      float acc[16];
      #pragma unroll
      for (int r=0;r<16;++r) acc[r]=0.f;
      #pragma unroll 2
      for (int k4=0;k4<128;++k4){
        int k = k4*4;
        float w0 = aw[(size_t)(k+0)*512 + tid];
        float w1 = aw[(size_t)(k+1)*512 + tid];
        float w2 = aw[(size_t)(k+2)*512 + tid];
        float w3 = aw[(size_t)(k+3)*512 + tid];
        #pragma unroll
        for (int r=0;r<16;++r){
          float4 fv = f4r[r*128 + k4];
          acc[r] += fv.x*w0 + fv.y*w1 + fv.z*w2 + fv.w*w3;
        }
      }
      float lb = ab[tid];
      #pragma unroll
      for (int r=0;r<16;++r){
        float l = acc[r] + lb;
        float x = f4[r*512 + tid];
        float mn = fmaxf(m, l);
        float e0 = __expf(m - mn);
        float e1 = __expf(l - mn);
        s = s*e0 + e1;
        a = a*e0 + x*e1;
        m = mn;
        fx = fmaxf(fx, x);
      }
    }
  }
  part[(size_t)chunk*512 + tid] = make_float4(m, s, a, fx);
}

__global__ __launch_bounds__(256) void attmerge_kernel(const float4* __restrict__ part, float* __restrict__ feat){
  int t = blockIdx.x*256 + threadIdx.x;
  if (t >= BB*512) return;
  int b = t >> 9, f = t & 511;
  float m=-INFINITY, s=0.f, a=0.f, fx=0.f;
  for (int c=0;c<128;++c){
    float4 p = part[((size_t)(b*128 + c))*512 + f];
    float mn = fmaxf(m, p.x);
    float e0 = __expf(m - mn), e1 = __expf(p.x - mn);
    s = s*e0 + p.y*e1;
    a = a*e0 + p.z*e1;
    m = mn;
    fx = fmaxf(fx, p.w);
  }
  feat[(size_t)b*1024 + f] = fx;
  feat[(size_t)b*1024 + 512 + f] = a / s;
}

// ------------- head MLP v2: split-K with atomics -------------
// init: Y[row][j] = bias[j] for rows 0,1
__global__ __launch_bounds__(256) void headinit_kernel(const float* __restrict__ bias, float* __restrict__ Y, int J){
  int i = blockIdx.x*256 + threadIdx.x;
  if (i < 2*J) Y[i] = bias[i >= J ? i - J : i];
}
// partial: grid (J/64, K/128); block 256 = 64 cols x 4 k-slices of 32
__global__ __launch_bounds__(256) void headpart_kernel(
    const float* __restrict__ X, const float* __restrict__ W, float* __restrict__ Y,
    int K, int J, int relu_in)
{
  const int j  = blockIdx.x*64 + (threadIdx.x & 63);
  const int k0 = blockIdx.y*128 + (threadIdx.x >> 6)*32;
  float acc0 = 0.f, acc1 = 0.f;
  #pragma unroll 8
  for (int k = 0; k < 32; ++k){
    float x0 = X[k0+k], x1 = X[K + k0+k];
    if (relu_in){ x0 = fmaxf(x0, 0.f); x1 = fmaxf(x1, 0.f); }
    float w = W[(size_t)(k0+k)*J + j];
    acc0 += x0*w; acc1 += x1*w;
  }
  atomicAdd(&Y[j], acc0);
  atomicAdd(&Y[J+j], acc1);
}

extern "C" void kernel_launch(void* const* d_in, const int* in_sizes, int n_in,
                              void* d_out, int out_size, void* d_ws, size_t ws_size,
                              hipStream_t stream)
{
  const float* pts    = (const float*)d_in[0];
  const float* na1w1  = (const float*)d_in[1];
  const float* na1b1  = (const float*)d_in[2];
  const float* na1w2  = (const float*)d_in[3];
  const float* na1b2  = (const float*)d_in[4];
  const float* na2w   = (const float*)d_in[5];
  const float* na2b   = (const float*)d_in[6];
  const float* na3w   = (const float*)d_in[7];
  const float* na3b   = (const float*)d_in[8];
  const float* r1aw   = (const float*)d_in[9];
  const float* r1ab   = (const float*)d_in[10];
  const float* r1bw   = (const float*)d_in[11];
  const float* r1bb   = (const float*)d_in[12];
  const float* r1sw   = (const float*)d_in[13];
  const float* r1sb   = (const float*)d_in[14];
  const float* r2aw   = (const float*)d_in[15];
  const float* r2ab   = (const float*)d_in[16];
  const float* r2bw   = (const float*)d_in[17];
  const float* r2bb   = (const float*)d_in[18];
  const float* r2sw   = (const float*)d_in[19];
  const float* r2sb   = (const float*)d_in[20];
  const float* fusew  = (const float*)d_in[21];
  const float* fuseb  = (const float*)d_in[22];
  const float* attw   = (const float*)d_in[23];
  const float* attb   = (const float*)d_in[24];
  const float* fc1w   = (const float*)d_in[25];
  const float* fc1b   = (const float*)d_in[26];
  const float* fc2w   = (const float*)d_in[27];
  const float* fc2b   = (const float*)d_in[28];
  const float* fc3w   = (const float*)d_in[29];
  const float* fc3b   = (const float*)d_in[30];

  if (n_in < 31) return;
  if (in_sizes[0] != NPTS*3) return;
  if (in_sizes[21] != 352*512) return;
  if (in_sizes[29] != 1024*1024) return;

  // Workspace layout (float offsets).
  const size_t o_ftr1 = 0;
  const size_t o_ftr2 = 524288;
  const size_t o_ftr3 = 1572864;
  const size_t o_knn  = 1572864;
  const size_t o_part = 3670016;
  const size_t o_g2   = 4194304;
  const size_t o_g3   = 4194432;
  const size_t o_feat = 4194688;
  const size_t o_h1   = 4196736;
  const size_t o_h2   = 4197760;        // end 4199808
  const size_t o_pfw  = 4199808;        // 352*512 bf16 = 90112 floats
  const size_t o_paw  = o_pfw + 90112;  // 512*512 bf16 = 131072 floats -> end 4420992
  const size_t base_bytes = 4199808ull * 4ull;
  const size_t mfma_bytes = 4420992ull * 4ull;
  if (ws_size < base_bytes) return;
  const bool use_mfma = (ws_size >= mfma_bytes);

  float* ws = (float*)d_ws;
  float*  ftr1 = ws + o_ftr1;
  float*  ftr2 = ws + o_ftr2;
  float*  ftr3 = ws + o_ftr3;
  int*    knn  = (int*)(ws + o_knn);
  float4* part = (float4*)(ws + o_part);
  float*  g2   = ws + o_g2;
  float*  g3   = ws + o_g3;
  float*  feat = ws + o_feat;
  float*  h1   = ws + o_h1;
  float*  h2   = ws + o_h2;
  s16*    pfw  = (s16*)(ws + o_pfw);
  s16*    paw  = (s16*)(ws + o_paw);

  zero_kernel<<<2, 256, 0, stream>>>(g2, 384);
  if (use_mfma){
    packw_kernel<<<11*32, 64, 0, stream>>>(fusew, pfw);
    packw_kernel<<<16*32, 64, 0, stream>>>(attw, paw);
  }
  knn_kernel<<<NPTS, 64, 0, stream>>>(pts, knn);
  nbr_kernel<<<NPTS*16/256, 256, 0, stream>>>(pts, knn, na1w1, na1b1, na1w2, na1b2,
                                              na2w, na2b, na3w, na3b, ftr1);
  resblock_kernel<32,64><<<NPTS/16, 256, 0, stream>>>(ftr1, 32, nullptr, 0,
                                                      r1aw, r1ab, r1bw, r1bb, r1sw, r1sb, ftr2);
  colmax_kernel<<<dim3(32,2), 256, 0, stream>>>(ftr2, g2, 64);
  resblock_kernel<128,128><<<NPTS/16, 256, 0, stream>>>(ftr2, 64, g2, 1,
                                                        r2aw, r2ab, r2bw, r2bb, r2sw, r2sb, ftr3);
  colmax_kernel<<<dim3(32,2), 256, 0, stream>>>(ftr3, g3, 128);
  if (use_mfma){
    fuseatt_mfma<<<NPTS/64, 512, 0, stream>>>(ftr1, ftr2, ftr3, g3,
                                              pfw, fuseb, paw, attb, part);
  } else {
    fuseatt_kernel<<<NPTS/64, 512, 0, stream>>>(ftr1, ftr2, ftr3, g3,
                                                fusew, fuseb, attw, attb, part);
  }
  attmerge_kernel<<<4, 256, 0, stream>>>(part, feat);
  // head MLP v2: init bias + split-K atomic partials; relu folded into consumer reads
  headinit_kernel<<<4, 256, 0, stream>>>(fc1b, h1, 512);
  headpart_kernel<<<dim3(8, 8),  256, 0, stream>>>(feat, fc1w, h1, 1024, 512, 0);
  headinit_kernel<<<8, 256, 0, stream>>>(fc2b, h2, 1024);
  headpart_kernel<<<dim3(16, 4), 256, 0, stream>>>(h1, fc2w, h2, 512, 1024, 1);
  headinit_kernel<<<8, 256, 0, stream>>>(fc3b, (float*)d_out, 1024);
  headpart_kernel<<<dim3(16, 8), 256, 0, stream>>>(h2, fc3w, (float*)d_out, 1024, 1024, 1);
}